// Round 16
// baseline (266.217 us; speedup 1.0000x reference)
//
#include <hip/hip_runtime.h>
#include <cstdint>
#include <cstddef>
#include <cstdio>

// ---------------- constants ----------------
#define B_   2
#define T_   1024
#define C_   1024
#define H_   16
#define HS_  64
#define FFN_ 3072

typedef __bf16   bf16x8 __attribute__((ext_vector_type(8)));
typedef float    f32x4  __attribute__((ext_vector_type(4)));
typedef float    f32x16 __attribute__((ext_vector_type(16)));
typedef uint16_t u16x8  __attribute__((ext_vector_type(8)));

__device__ __forceinline__ uint16_t f2bf(float f){
  uint32_t u = __float_as_uint(f);
  u += 0x7FFFu + ((u >> 16) & 1u);          // RNE
  return (uint16_t)(u >> 16);
}
__device__ __forceinline__ float bf2f(uint16_t h){
  return __uint_as_float(((uint32_t)h) << 16);
}
__device__ __forceinline__ bf16x8 ldb8(const uint16_t* p){
  return __builtin_bit_cast(bf16x8, *reinterpret_cast<const u16x8*>(p));
}
__device__ __forceinline__ f32x4 mfma16(bf16x8 a, bf16x8 b, f32x4 c){
  return __builtin_amdgcn_mfma_f32_16x16x32_bf16(a, b, c, 0, 0, 0);
}

// async global->LDS, 16B per lane
typedef __attribute__((address_space(1))) const uint32_t* gas_t;
typedef __attribute__((address_space(3))) uint32_t* las_t;
__device__ __forceinline__ void gl_lds16(const uint16_t* g, uint16_t* l){
  __builtin_amdgcn_global_load_lds((gas_t)g, (las_t)l, 16, 0, 0);
}

// ---------------- fused prologue: weight transposes + biases + LN1 ----------------
__global__ __launch_bounds__(256) void k_prep(
    const float* __restrict__ Wq, const float* __restrict__ Wk,
    const float* __restrict__ Wv, const float* __restrict__ Wo,
    const float* __restrict__ Wkg, const float* __restrict__ Wvg,
    const float* __restrict__ Wwg,
    const float* __restrict__ bq, const float* __restrict__ bk,
    const float* __restrict__ bv, const float* __restrict__ bkg,
    const float* __restrict__ bvg,
    const float* __restrict__ x, const float* __restrict__ ln1w,
    const float* __restrict__ ln1b,
    uint16_t* __restrict__ WqT, uint16_t* __restrict__ WkT,
    uint16_t* __restrict__ WvT, uint16_t* __restrict__ WoT,
    uint16_t* __restrict__ Wff, uint16_t* __restrict__ WwgT,
    float* __restrict__ bcat, float* __restrict__ bcatFF,
    uint16_t* __restrict__ xs)
{
  __shared__ float tile[32][33];
  __shared__ float red[8];
  const int id = blockIdx.x;
  const int tid = threadIdx.x;

  if (id < 13312){
    if (id < 4096){
      int w = id >> 10, r = id & 1023;
      const float* in = (w==0)?Wq:(w==1)?Wk:(w==2)?Wv:Wo;
      uint16_t* outp  = (w==0)?WqT:(w==1)?WkT:(w==2)?WvT:WoT;
      int c0 = (r & 31)*32, r0 = (r >> 5)*32;
      int tx = tid & 31, ty = tid >> 5;
      #pragma unroll
      for (int i=0;i<4;i++) tile[ty+i*8][tx] = in[(size_t)(r0+ty+i*8)*1024 + c0+tx];
      __syncthreads();
      #pragma unroll
      for (int i=0;i<4;i++) outp[(size_t)(c0+ty+i*8)*1024 + r0+tx] = f2bf(tile[tx][ty+i*8]);
    } else if (id < 10240){
      int r = id - 4096; int s = r / 3072; r -= s*3072;
      const float* in = s ? Wvg : Wkg;
      int c0 = (r % 96)*32, r0 = (r / 96)*32;
      int tx = tid & 31, ty = tid >> 5;
      #pragma unroll
      for (int i=0;i<4;i++) tile[ty+i*8][tx] = in[(size_t)(r0+ty+i*8)*3072 + c0+tx];
      __syncthreads();
      #pragma unroll
      for (int i=0;i<4;i++){
        int j = c0+ty+i*8;                       // ffn col 0..3071
        int row = ((j>>4)<<5) + (s<<4) + (j&15); // interleaved 16-wide groups
        Wff[(size_t)row*1024 + r0+tx] = f2bf(tile[tx][ty+i*8]);
      }
    } else {
      int r = id - 10240;
      int c0 = (r & 31)*32, r0 = (r >> 5)*32;
      int tx = tid & 31, ty = tid >> 5;
      #pragma unroll
      for (int i=0;i<4;i++) tile[ty+i*8][tx] = Wwg[(size_t)(r0+ty+i*8)*1024 + c0+tx];
      __syncthreads();
      #pragma unroll
      for (int i=0;i<4;i++) WwgT[(size_t)(c0+ty+i*8)*3072 + r0+tx] = f2bf(tile[tx][ty+i*8]);
    }
    return;
  }
  if (id < 13324){
    int i = (id - 13312)*256 + tid;   // 3072
    float v;
    if      (i < 1024) v = bq[i];
    else if (i < 2048) v = bk[i-1024];
    else               v = bv[i-2048];
    bcat[i] = v;
    return;
  }
  if (id < 13348){
    int i = (id - 13324)*256 + tid;   // 6144 interleaved
    int s = (i >> 4) & 1;
    int j = ((i >> 5) << 4) | (i & 15);
    bcatFF[i] = s ? bvg[j] : bkg[j];
    return;
  }
  // ---- LN1 + shift ----
  {
    int row = id - 13348;               // b*T + t
    int t = row & (T_-1);
    const float* xr = x + (size_t)row*C_;
    float4 v = reinterpret_cast<const float4*>(xr)[tid];
    float s  = v.x+v.y+v.z+v.w;
    float s2 = v.x*v.x+v.y*v.y+v.z*v.z+v.w*v.w;
    #pragma unroll
    for (int o=1;o<64;o<<=1){ s += __shfl_xor(s,o); s2 += __shfl_xor(s2,o); }
    int lane = tid & 63, wv = tid >> 6;
    if (lane == 0){ red[wv] = s; red[4+wv] = s2; }
    __syncthreads();
    s  = red[0]+red[1]+red[2]+red[3];
    s2 = red[4]+red[5]+red[6]+red[7];
    float mean = s * (1.f/1024.f);
    float var  = s2 * (1.f/1024.f) - mean*mean;
    float rs   = rsqrtf(var + 1e-5f);
    float vals[4] = {v.x, v.y, v.z, v.w};
    #pragma unroll
    for (int j=0;j<4;j++){
      int cc = tid*4 + j;
      float o_ = (vals[j]-mean)*rs*ln1w[cc] + ln1b[cc];
      uint16_t ob = f2bf(o_);
      if (cc < 512){
        if (t < T_-1) xs[(size_t)(row+1)*C_ + cc] = ob;
        if (t == 0)   xs[(size_t)row*C_ + cc] = 0;
      } else {
        xs[(size_t)row*C_ + cc] = ob;
      }
    }
  }
}

// ---------------- LayerNorm (plain) ----------------
__global__ __launch_bounds__(256) void k_ln(const float* __restrict__ in,
                                            const float* __restrict__ w,
                                            const float* __restrict__ bia,
                                            uint16_t* __restrict__ out){
  int row = blockIdx.x;
  const float* xr = in + (size_t)row*C_;
  float4 v = reinterpret_cast<const float4*>(xr)[threadIdx.x];
  float s  = v.x+v.y+v.z+v.w;
  float s2 = v.x*v.x+v.y*v.y+v.z*v.z+v.w*v.w;
  #pragma unroll
  for (int o=1;o<64;o<<=1){ s += __shfl_xor(s,o); s2 += __shfl_xor(s2,o); }
  __shared__ float red[8];
  int lane = threadIdx.x & 63, wid = threadIdx.x >> 6;
  if (lane == 0){ red[wid] = s; red[4+wid] = s2; }
  __syncthreads();
  s  = red[0]+red[1]+red[2]+red[3];
  s2 = red[4]+red[5]+red[6]+red[7];
  float mean = s * (1.f/1024.f);
  float var  = s2 * (1.f/1024.f) - mean*mean;
  float rs   = rsqrtf(var + 1e-5f);
  float vals[4] = {v.x, v.y, v.z, v.w};
  #pragma unroll
  for (int j=0;j<4;j++){
    int cc = threadIdx.x*4 + j;
    out[(size_t)row*C_ + cc] = f2bf((vals[j]-mean)*rs*w[cc] + bia[cc]);
  }
}

// ---------------- MFMA GEMM v4: BK=64, XOR-swizzled LDS (src + read swizzle) ----------------
enum { EPI_QKV=0, EPI_WO=2, EPI_GEGLU=3, EPI_FFN2=4 };

template<int EPI, int BN>
__global__ __launch_bounds__(256) void k_gemm2(
    const uint16_t* __restrict__ A, const uint16_t* __restrict__ Bt,
    const float* __restrict__ bias, void* __restrict__ outp,
    int M, int N, int K,
    const float* __restrict__ aux0, const float* __restrict__ aux1)
{
  __shared__ uint16_t As[128*64];     // 16 KB
  __shared__ uint16_t Bs[BN*64];      // 8/16 KB
  const int m0 = blockIdx.y*128, n0 = blockIdx.x*BN;
  const int tid = threadIdx.x;
  const int lane = tid & 63, wid = tid >> 6;
  const int wy = wid >> 1, wx = wid & 1;
  const int l16 = lane & 15, lr = lane >> 4;
  const int sw = l16 & 7;
  const int WN = BN/2;            // wave cols
  const int NW = BN/32;           // b-frags per wave
  const f32x4 z = {0.f,0.f,0.f,0.f};
  f32x4 acc[4][NW];
  #pragma unroll
  for (int m=0;m<4;m++)
    #pragma unroll
    for (int n=0;n<NW;n++) acc[m][n] = z;

  for (int k0 = 0; k0 < K; k0 += 64){
    #pragma unroll
    for (int r4=0;r4<4;r4++){
      int c = tid + r4*256;           // 1024 A-chunks
      int row = c >> 3, jp = c & 7;
      int col = ((jp ^ (row & 7)) << 3);
      gl_lds16(A + (size_t)(m0+row)*K + k0 + col, As + c*8);
    }
    #pragma unroll
    for (int r4=0;r4<BN/32;r4++){
      int c = tid + r4*256;           // BN*8 B-chunks
      int row = c >> 3, jp = c & 7;
      int col = ((jp ^ (row & 7)) << 3);
      gl_lds16(Bt + (size_t)(n0+row)*K + k0 + col, Bs + c*8);
    }
    __syncthreads();
    #pragma unroll
    for (int kk=0;kk<2;kk++){
      bf16x8 af[4], bfr[NW];
      #pragma unroll
      for (int m=0;m<4;m++)
        af[m] = ldb8(As + (wy*64 + m*16 + l16)*64 + (((lr + 4*kk) ^ sw) << 3));
      #pragma unroll
      for (int n=0;n<NW;n++)
        bfr[n] = ldb8(Bs + (wx*WN + n*16 + l16)*64 + (((lr + 4*kk) ^ sw) << 3));
      #pragma unroll
      for (int m=0;m<4;m++)
        #pragma unroll
        for (int n=0;n<NW;n++) acc[m][n] = mfma16(af[m], bfr[n], acc[m][n]);
    }
    __syncthreads();
  }
  if constexpr (EPI == EPI_QKV){
    // BN=128: wave covers one (kind,head); rotary pairs (d,d+16) are frags n=0,n=1
    const int colb = n0 + wx*WN;
    const int kind = colb >> 10;
    const int h = (colb >> 6) & 15;
    const float linvf = exp2f(-(float)l16 * 0.83048202f);  // 10000^(-l16/16)
    #pragma unroll
    for (int m=0;m<4;m++){
      #pragma unroll
      for (int r=0;r<4;r++){
        int row = m0 + wy*64 + m*16 + lr*4 + r;
        int bb = row >> 10, t = row & 1023;
        float v[NW];
        #pragma unroll
        for (int n=0;n<NW;n++) v[n] = acc[m][n][r] + bias[colb + n*16 + l16];
        if (kind < 2){
          float sn, cs;
          __sincosf((float)t * linvf, &sn, &cs);
          float r0 = v[0]*cs - v[1]*sn;
          float r1 = v[1]*cs + v[0]*sn;
          v[0] = r0; v[1] = r1;
          uint16_t* dst = (uint16_t*)outp + (size_t)kind*2097152;
          size_t basei = (((size_t)bb*16 + h)*1024 + t)*64;
          #pragma unroll
          for (int n=0;n<NW;n++) dst[basei + n*16 + l16] = f2bf(v[n]);
        } else {  // V transposed [b,h,d,t]
          uint16_t* dst = (uint16_t*)outp + (size_t)2*2097152;
          size_t basei = ((size_t)bb*16 + h)*65536;
          #pragma unroll
          for (int n=0;n<NW;n++) dst[basei + (size_t)(n*16 + l16)*1024 + t] = f2bf(v[n]);
        }
      }
    }
  } else if constexpr (EPI == EPI_GEGLU){
    // BN=128, interleaved Wff: frag n even = kg, n odd = vg (same thread pair)
    const int colb = n0 + wx*WN;
    #pragma unroll
    for (int m=0;m<4;m++){
      #pragma unroll
      for (int r=0;r<4;r++){
        int row = m0 + wy*64 + m*16 + lr*4 + r;
        #pragma unroll
        for (int np=0;np<NW;np+=2){
          float kk = acc[m][np][r]   + bias[colb + np*16 + l16];
          float vv = acc[m][np+1][r] + bias[colb + (np+1)*16 + l16];
          float gl = 0.5f*kk*(1.f + erff(kk*0.70710678118f));
          int j = ((colb>>5) + (np>>1))*16 + l16;      // original ffn col
          ((uint16_t*)outp)[(size_t)row*3072 + j] = f2bf(gl*vv);
        }
      }
    }
  } else {
    #pragma unroll
    for (int m=0;m<4;m++){
      #pragma unroll
      for (int n=0;n<NW;n++){
        int col = n0 + wx*WN + n*16 + l16;
        float bc_ = bias ? bias[col] : 0.f;
        #pragma unroll
        for (int r=0;r<4;r++){
          int row = m0 + wy*64 + m*16 + lr*4 + r;
          float v = acc[m][n][r] + bc_;
          if constexpr (EPI == EPI_WO){
            int t = row & (T_-1);
            ((float*)outp)[(size_t)row*N + col] = aux1[(size_t)row*N + col] + v*aux0[t];
          } else { // EPI_FFN2
            ((float*)outp)[(size_t)row*N + col] = aux0[(size_t)row*N + col] + v;
          }
        }
      }
    }
  }
}

// ---------------- pass A: softmax stats via per-lane ONLINE accumulation ----------------
__global__ __launch_bounds__(256) void k_stats(const uint16_t* __restrict__ q,
                                               const uint16_t* __restrict__ kmat,
                                               float* __restrict__ sm, float* __restrict__ sl){
  int bh = blockIdx.x, qb = blockIdx.y;
  int lane = threadIdx.x & 63, wid = threadIdx.x >> 6;
  int l16 = lane & 15, lr = lane >> 4;
  int r0 = qb*64 + wid*16;
  const uint16_t* qh = q    + (size_t)bh*T_*HS_;
  const uint16_t* kh = kmat + (size_t)bh*T_*HS_;
  int kq = lr*8;
  bf16x8 a0 = ldb8(qh + (size_t)(r0 + l16)*HS_ + kq);
  bf16x8 a1 = ldb8(qh + (size_t)(r0 + l16)*HS_ + kq + 32);
  float m_[4], l_[4]; int rows[4];
  #pragma unroll
  for (int r=0;r<4;r++){ m_[r] = -1e30f; l_[r] = 0.f; rows[r] = r0 + lr*4 + r; }
  int ktmax = (r0 + 15) >> 4;
  for (int kt = 0; kt <= ktmax; kt++){
    bf16x8 b0 = ldb8(kh + (size_t)(kt*16 + l16)*HS_ + kq);
    bf16x8 b1 = ldb8(kh + (size_t)(kt*16 + l16)*HS_ + kq + 32);
    f32x4 s = {0.f,0.f,0.f,0.f};
    s = mfma16(a0, b0, s);
    s = mfma16(a1, b1, s);
    int kcol = kt*16 + l16;
    #pragma unroll
    for (int r=0;r<4;r++){
      float sv = (kcol <= rows[r]) ? s[r]*0.125f : -3.0e38f;
      float mn = fmaxf(m_[r], sv);
      l_[r] = l_[r]*__expf(m_[r] - mn) + __expf(sv - mn);
      m_[r] = mn;
    }
  }
  #pragma unroll
  for (int o=1;o<16;o<<=1){
    #pragma unroll
    for (int r=0;r<4;r++){
      float mo = __shfl_xor(m_[r], o);
      float lo = __shfl_xor(l_[r], o);
      float mn = fmaxf(m_[r], mo);
      l_[r] = l_[r]*__expf(m_[r] - mn) + lo*__expf(mo - mn);
      m_[r] = mn;
    }
  }
  if (l16 == 0){
    #pragma unroll
    for (int r=0;r<4;r++){
      sm[(size_t)bh*T_ + rows[r]] = m_[r];
      sl[(size_t)bh*T_ + rows[r]] = l_[r];
    }
  }
}

// ---------------- fused attention v10: persistent queue + V-prefetch + K-pipeline ----------------
// 512 blocks x 512 thr (2 blocks/CU, LDS-bound; 256-VGPR budget).
// K frags loaded one TILE-PAIR ahead (issued after B1, consumed next pair's phase 1).
__global__ __launch_bounds__(512, 2) void k_attn(
    const uint16_t* __restrict__ q, const uint16_t* __restrict__ kmat,
    const uint16_t* __restrict__ vT,
    const float* __restrict__ sm, const float* __restrict__ sl,
    const float* __restrict__ tw, const float* __restrict__ alpha,
    const float* __restrict__ beta, const float* __restrict__ mixw,
    uint16_t* __restrict__ py, int* __restrict__ counter)
{
  __shared__ uint32_t U32[2*4096];     // 32 KB: two tile buffers
  __shared__ uint16_t Cm[2*8320];      // 33.3 KB
  __shared__ uint16_t TWL[16*160];     // 5 KB (bf16)
  __shared__ int s_item;

  const int tid = threadIdx.x;
  const int lane = tid & 63;
  const int wid = __builtin_amdgcn_readfirstlane(tid >> 6);
  const int l16 = lane & 15, lr = lane >> 4;
  const int l32 = lane & 31, g32 = lane >> 5;

  // mix-weight B-fragment (item-independent)
  bf16x8 mwf;
  {
    u16x8 t8;
    #pragma unroll
    for (int j=0;j<8;j++){
      float v = (l32 < 16) ? mixw[l32*16 + g32*8 + j] : 0.f;
      t8[j] = f2bf(v);
    }
    mwf = __builtin_bit_cast(bf16x8, t8);
  }
  const f32x4 z = {0.f,0.f,0.f,0.f};

  for (;;){
    if (tid == 0) s_item = atomicAdd(counter, 1);
    __syncthreads();
    const int item = s_item;
    if (item >= 576) break;

    // decode item -> (b, qt, kc)
    const int b = (item >= 288) ? 1 : 0;
    int j = item - b*288;
    int g = 0;
    while (4*(g+1)*(g+2) <= j) g++;
    int jj = j - 4*g*(g+1);
    const int qt = 8*g + jj/(g+1);
    const int kc = jj % (g+1);

    const int q0 = qt*16, ck0 = kc*128;
    const int lc = min(127, q0 + 15 - ck0);
    const int nt = (lc >> 5) + 1;

    // per-item staging
    const int base = 1008 - q0 + ck0;
    for (int i = tid; i < 16*144; i += 512){
      int h = i / 144, t = i - h*144;
      int gi = base + t;
      TWL[h*160 + t] = (gi <= 1023) ? f2bf(tw[h*1024 + gi]) : (uint16_t)0;
    }
    float SM[2][4], BSL[2][4];
    bf16x8 qa[2][2];
    #pragma unroll
    for (int h2=0; h2<2; ++h2){
      int h = 2*wid + h2, bh = b*16 + h;
      float4 s4 = *reinterpret_cast<const float4*>(sm   + (size_t)bh*1024 + q0 + lr*4);
      float4 l4 = *reinterpret_cast<const float4*>(sl   + (size_t)bh*1024 + q0 + lr*4);
      float4 b4 = *reinterpret_cast<const float4*>(beta + (size_t)h*1024  + q0 + lr*4);
      SM[h2][0]=s4.x; SM[h2][1]=s4.y; SM[h2][2]=s4.z; SM[h2][3]=s4.w;
      BSL[h2][0]=b4.x/l4.x; BSL[h2][1]=b4.y/l4.y; BSL[h2][2]=b4.z/l4.z; BSL[h2][3]=b4.w/l4.w;
      #pragma unroll
      for (int kk=0;kk<2;kk++)
        qa[h2][kk] = ldb8(q + ((size_t)bh*1024 + q0 + l16)*64 + kk*32 + lr*8);
    }
    f32x4 acc[2][4];
    #pragma unroll
    for (int oo=0;oo<2;oo++) for (int n=0;n<4;n++) acc[oo][n] = z;

    // K fragment pipeline: prefetch pair 0
    bf16x8 kf[2][2][2][2];   // [half][h2][kk][rh]
    {
      const int nt0 = (nt >= 2) ? 2 : 1;
      #pragma unroll
      for (int half = 0; half < 2; ++half){
        if (half < nt0){
          const int k0 = ck0 + half*32;
          #pragma unroll
          for (int h2=0;h2<2;h2++){
            const uint16_t* kh = kmat + ((size_t)(b*16 + 2*wid + h2)*1024 + k0)*64;
            #pragma unroll
            for (int kk=0;kk<2;kk++){
              kf[half][h2][kk][0] = ldb8(kh + (size_t)(l16)*64      + kk*32 + lr*8);
              kf[half][h2][kk][1] = ldb8(kh + (size_t)(16 + l16)*64 + kk*32 + lr*8);
            }
          }
        }
      }
    }

    __syncthreads();   // TWL ready

    for (int tp = 0; tp < nt; tp += 2){
      const int ntile = (nt - tp >= 2) ? 2 : 1;
      bf16x8 vf[2][2][4];   // [half][oo][n], live across B1/B2
      // ---- phase 1: V prefetch + QK^T (prefetched K) + u ----
      #pragma unroll
      for (int half = 0; half < 2; ++half){
        if (half >= ntile) break;
        const int t = tp + half;
        const int k0 = ck0 + t*32;
        #pragma unroll
        for (int oo=0;oo<2;oo++){
          const uint16_t* vh = vT + (size_t)(b*16 + 2*wid + oo)*65536;
          #pragma unroll
          for (int n=0;n<4;n++)
            vf[half][oo][n] = ldb8(vh + (size_t)(n*16 + l16)*1024 + k0 + lr*8);
        }
        float al0[2], al1[2];
        #pragma unroll
        for (int n=0;n<2;n++){
          int kg = k0 + n*16 + l16;
          al0[n] = alpha[(2*wid+0)*1024 + kg];
          al1[n] = alpha[(2*wid+1)*1024 + kg];
        }
        f32x4 s[2][2];
        s[0][0]=z; s[0][1]=z; s[1][0]=z; s[1][1]=z;
        #pragma unroll
        for (int h2=0;h2<2;h2++){
          #pragma unroll
          for (int kk=0;kk<2;kk++){
            s[h2][0] = mfma16(qa[h2][kk], kf[half][h2][kk][0], s[h2][0]);
            s[h2][1] = mfma16(qa[h2][kk], kf[half][h2][kk][1], s[h2][1]);
          }
        }
        uint32_t* Ub = U32 + half*4096;
        #pragma unroll
        for (int n=0;n<2;n++){
          int kloc = n*16 + l16;
          int kg = k0 + kloc;
          #pragma unroll
          for (int r=0;r<4;r++){
            int qloc = lr*4 + r;
            bool ok = (kg <= q0 + qloc);
            int twi = 15 - qloc + (kg - ck0);
            float u0 = 0.f, u1 = 0.f;
            if (ok){
              u0 = __expf(s[0][n][r]*0.125f - SM[0][r]) * BSL[0][r] * al0[n] * bf2f(TWL[(2*wid+0)*160 + twi]);
              u1 = __expf(s[1][n][r]*0.125f - SM[1][r]) * BSL[1][r] * al1[n] * bf2f(TWL[(2*wid+1)*160 + twi]);
            }
            uint32_t pk = (uint32_t)f2bf(u0) | ((uint32_t)f2bf(u1) << 16);
            Ub[wid*512 + qloc*32 + ((kloc + 8*(qloc>>2)) & 31)] = pk;
          }
        }
      }
      __syncthreads();   // B1: U buffers complete
      // ---- K prefetch for pair tp+2 (consumed next iteration) ----
      {
        const int tpn = tp + 2;
        #pragma unroll
        for (int half = 0; half < 2; ++half){
          if (tpn + half < nt){
            const int k0 = ck0 + (tpn + half)*32;
            #pragma unroll
            for (int h2=0;h2<2;h2++){
              const uint16_t* kh = kmat + ((size_t)(b*16 + 2*wid + h2)*1024 + k0)*64;
              #pragma unroll
              for (int kk=0;kk<2;kk++){
                kf[half][h2][kk][0] = ldb8(kh + (size_t)(l16)*64      + kk*32 + lr*8);
                kf[half][h2][kk][1] = ldb8(kh + (size_t)(16 + l16)*64 + kk*32 + lr*8);
              }
            }
          }
        }
      }
      // ---- phase 2: head-mix via 32x32x16 MFMA ----
      #pragma unroll
      for (int half = 0; half < 2; ++half){
        if (half >= ntile) break;
        const uint32_t* Ub = U32 + half*4096;
        uint16_t* Cb = Cm + half*8320;
        #pragma unroll
        for (int cc=0; cc<2; ++cc){
          int qrow = wid*2 + cc;
          int pbase = qrow*32;
          int swz = (l32 + 8*(qrow>>2)) & 31;
          u16x8 a8;
          uint32_t* a32 = reinterpret_cast<uint32_t*>(&a8);
          #pragma unroll
          for (int jv=0;jv<4;jv++)
            a32[jv] = Ub[(4*g32 + jv)*512 + pbase + swz];
          bf16x8 a = __builtin_bit_cast(bf16x8, a8);
          f32x16 zz{};
          __builtin_amdgcn_s_setprio(1);
          f32x16 dd = __builtin_amdgcn_mfma_f32_32x32x16_bf16(a, mwf, zz, 0, 0, 0);
          __builtin_amdgcn_s_setprio(0);
          if (l32 < 16){
            int o = l32;
            #pragma unroll
            for (int rg=0; rg<4; ++rg){
              int p0 = pbase + rg*8 + g32*4;
              uint32_t w0 = (uint32_t)f2bf(dd[4*rg+0]) | ((uint32_t)f2bf(dd[4*rg+1]) << 16);
              uint32_t w1 = (uint32_t)f2bf(dd[4*rg+2]) | ((uint32_t)f2bf(dd[4*rg+3]) << 16);
              uint2 pk2; pk2.x = w0; pk2.y = w1;
              *reinterpret_cast<uint2*>(Cb + (size_t)o*520 + p0) = pk2;
            }
          }
        }
      }
      __syncthreads();   // B2: Cm buffers complete
      // ---- phase 3: PV both halves with prefetched V ----
      #pragma unroll
      for (int half = 0; half < 2; ++half){
        if (half >= ntile) break;
        const uint16_t* Cb = Cm + half*8320;
        #pragma unroll
        for (int oo=0;oo<2;oo++){
          int o = 2*wid + oo;
          bf16x8 cf = ldb8(Cb + (size_t)o*520 + l16*32 + lr*8);
          __builtin_amdgcn_s_setprio(1);
          #pragma unroll
          for (int n=0;n<4;n++)
            acc[oo][n] = mfma16(cf, vf[half][oo][n], acc[oo][n]);
          __builtin_amdgcn_s_setprio(0);
        }
      }
    }

    uint16_t* po = py + (((size_t)(b*64 + qt))*8 + kc)*16384;
    #pragma unroll
    for (int oo=0;oo<2;oo++){
      int o = 2*wid + oo;
      #pragma unroll
      for (int n=0;n<4;n++)
        #pragma unroll
        for (int r=0;r<4;r++){
          int qloc = lr*4 + r;
          po[o*1024 + qloc*64 + n*16 + l16] = f2bf(acc[oo][n][r]);
        }
    }
    __syncthreads();   // all phases done before next pop / LDS reuse
  }
}

// ---------------- reduce bf16 partials -> ybuf bf16 [B,T,C] ----------------
__global__ void k_yred(const uint16_t* __restrict__ py, uint16_t* __restrict__ y){
  int idx = blockIdx.x*256 + threadIdx.x;   // 262144, one bf16x8 each
  int d8 = idx & 7, qq = (idx>>3)&15, o = (idx>>7)&15, qt = (idx>>11)&63, b = idx>>17;
  int nch = (qt>>3) + 1;
  const uint16_t* p0 = py + (((size_t)(b*64+qt))*8)*16384 + o*1024 + qq*64 + d8*8;
  float s[8] = {0,0,0,0,0,0,0,0};
  for (int kc=0; kc<nch; kc++){
    u16x8 v = *reinterpret_cast<const u16x8*>(p0 + (size_t)kc*16384);
    #pragma unroll
    for (int e=0;e<8;e++) s[e] += bf2f(v[e]);
  }
  int t = qt*16 + qq;
  u16x8 w;
  #pragma unroll
  for (int e=0;e<8;e++) w[e] = f2bf(s[e]);
  *reinterpret_cast<u16x8*>(y + ((size_t)(b*1024 + t))*1024 + o*64 + d8*8) = w;
}

// ---------------- host ----------------
extern "C" void kernel_launch(void* const* d_in, const int* in_sizes, int n_in,
                              void* d_out, int out_size, void* d_ws, size_t ws_size,
                              hipStream_t stream)
{
  const float* x      = (const float*)d_in[0];
  const float* ln1w   = (const float*)d_in[1];
  const float* ln1b   = (const float*)d_in[2];
  const float* ln2w   = (const float*)d_in[3];
  const float* ln2b   = (const float*)d_in[4];
  const float* Wq     = (const float*)d_in[5];
  const float* bq     = (const float*)d_in[6];
  const float* Wk     = (const float*)d_in[7];
  const float* bk     = (const float*)d_in[8];
  const float* Wv     = (const float*)d_in[9];
  const float* bv     = (const float*)d_in[10];
  const float* Wo     = (const float*)d_in[11];
  const float* bo     = (const float*)d_in[12];
  const float* tw     = (const float*)d_in[13];
  const float* talpha = (const float*)d_in[14];
  const float* tbeta  = (const float*)d_in[15];
  const float* tgamma = (const float*)d_in[16];
  const float* mixw   = (const float*)d_in[17];
  const float* Wkg    = (const float*)d_in[18];
  const float* bkg    = (const float*)d_in[19];
  const float* Wvg    = (const float*)d_in[20];
  const float* bvg    = (const float*)d_in[21];
  const float* Wwg    = (const float*)d_in[22];
  const float* bwg    = (const float*)d_in[23];

  char* ws = (char*)d_ws;
  size_t off = 0;
  auto alloc = [&](size_t bytes)->char*{
    char* p = ws + off; off += (bytes + 255) & ~(size_t)255; return p;
  };
  int*      counter = (int*)alloc(256);
  uint16_t* WqT  = (uint16_t*)alloc((size_t)C_*C_*2);     // contiguous q|k|v
  uint16_t* WkT  = (uint16_t*)alloc((size_t)C_*C_*2);
  uint16_t* WvT  = (uint16_t*)alloc((size_t)C_*C_*2);
  uint16_t* WoT  = (uint16_t*)alloc((size_t)C_*C_*2);
  uint16_t* Wff  = (uint16_t*)alloc((size_t)2*FFN_*C_*2); // interleaved kg|vg
  uint16_t* WwgT = (uint16_t*)alloc((size_t)C_*FFN_*2);
  uint16_t* xs   = (uint16_t*)alloc((size_t)B_*T_*C_*2);
  uint16_t* qbuf = (uint16_t*)alloc((size_t)B_*T_*C_*2);  // contiguous q|k|vT
  uint16_t* kbuf = (uint16_t*)alloc((size_t)B_*T_*C_*2);
  uint16_t* vT   = (uint16_t*)alloc((size_t)B_*T_*C_*2);
  float*    sm   = (float*)alloc((size_t)B_*H_*T_*4);
  float*    sl   = (float*)alloc((size_t)B_*H_*T_*4);
  uint16_t* ybuf = (uint16_t*)alloc((size_t)B_*T_*C_*2);
  float*    x1   = (float*)alloc((size_t)B_*T_*C_*4);
  float*    bcat   = (float*)alloc((size_t)3072*4);
  float*    bcatFF = (float*)alloc((size_t)6144*4);
  char*     region = alloc((size_t)33*1024*1024);
  uint16_t* py  = (uint16_t*)region;                       // 32 MB bf16 partials
  uint16_t* gb  = (uint16_t*)region;                       // 12.6 MB (after attn done)

  if (off > ws_size){
    fprintf(stderr, "kernel_launch: ws too small (%zu needed, %zu given)\n", off, ws_size);
    return;
  }

  hipMemsetAsync(counter, 0, 4, stream);

  dim3 blk(256);
  // fused prologue: 7 transposes + biases + LN1/shift
  k_prep<<<15396, blk, 0, stream>>>(Wq, Wk, Wv, Wo, Wkg, Wvg, Wwg,
                                    bq, bk, bv, bkg, bvg,
                                    x, ln1w, ln1b,
                                    WqT, WkT, WvT, WoT, Wff, WwgT,
                                    bcat, bcatFF, xs);

  // fused QKV (N=3072) with RoPE + scatter epilogue, BN=128
  k_gemm2<EPI_QKV,128><<<dim3(24,16), blk, 0, stream>>>(xs, WqT, bcat, qbuf, 2048, 3072, 1024, nullptr, nullptr);

  k_stats<<<dim3(B_*H_, T_/64), blk, 0, stream>>>(qbuf, kbuf, sm, sl);
  k_attn<<<dim3(512), dim3(512), 0, stream>>>(qbuf, kbuf, vT, sm, sl,
                                              tw, talpha, tbeta, mixw, py, counter);
  k_yred<<<1024, blk, 0, stream>>>(py, ybuf);

  k_gemm2<EPI_WO,64><<<dim3(16,16), blk, 0, stream>>>(ybuf, WoT, bo, x1, 2048, 1024, 1024, tgamma, x);

  k_ln<<<B_*T_, blk, 0, stream>>>(x1, ln2w, ln2b, xs);

  // fused FFN-up + GEGLU (N=6144 interleaved -> gb 3072)
  k_gemm2<EPI_GEGLU,128><<<dim3(48,16), blk, 0, stream>>>(xs, Wff, bcatFF, gb, 2048, 6144, 1024, nullptr, nullptr);
  k_gemm2<EPI_FFN2,64><<<dim3(16,16), blk, 0, stream>>>(gb, WwgT, bwg, d_out, 2048, 1024, 3072, x1, nullptr);
}

// Round 17
// 249.963 us; speedup vs baseline: 1.0650x; 1.0650x over previous
//
#include <hip/hip_runtime.h>
#include <cstdint>
#include <cstddef>
#include <cstdio>

// ---------------- constants ----------------
#define B_   2
#define T_   1024
#define C_   1024
#define H_   16
#define HS_  64
#define FFN_ 3072

typedef __bf16   bf16x8 __attribute__((ext_vector_type(8)));
typedef float    f32x4  __attribute__((ext_vector_type(4)));
typedef float    f32x16 __attribute__((ext_vector_type(16)));
typedef uint16_t u16x8  __attribute__((ext_vector_type(8)));

__device__ __forceinline__ uint16_t f2bf(float f){
  uint32_t u = __float_as_uint(f);
  u += 0x7FFFu + ((u >> 16) & 1u);          // RNE
  return (uint16_t)(u >> 16);
}
__device__ __forceinline__ float bf2f(uint16_t h){
  return __uint_as_float(((uint32_t)h) << 16);
}
__device__ __forceinline__ bf16x8 ldb8(const uint16_t* p){
  return __builtin_bit_cast(bf16x8, *reinterpret_cast<const u16x8*>(p));
}
__device__ __forceinline__ f32x4 mfma16(bf16x8 a, bf16x8 b, f32x4 c){
  return __builtin_amdgcn_mfma_f32_16x16x32_bf16(a, b, c, 0, 0, 0);
}

// async global->LDS, 16B per lane
typedef __attribute__((address_space(1))) const uint32_t* gas_t;
typedef __attribute__((address_space(3))) uint32_t* las_t;
__device__ __forceinline__ void gl_lds16(const uint16_t* g, uint16_t* l){
  __builtin_amdgcn_global_load_lds((gas_t)g, (las_t)l, 16, 0, 0);
}

// ---------------- fused prologue: weight transposes + biases + LN1 ----------------
__global__ __launch_bounds__(256) void k_prep(
    const float* __restrict__ Wq, const float* __restrict__ Wk,
    const float* __restrict__ Wv, const float* __restrict__ Wo,
    const float* __restrict__ Wkg, const float* __restrict__ Wvg,
    const float* __restrict__ Wwg,
    const float* __restrict__ bq, const float* __restrict__ bk,
    const float* __restrict__ bv, const float* __restrict__ bkg,
    const float* __restrict__ bvg,
    const float* __restrict__ x, const float* __restrict__ ln1w,
    const float* __restrict__ ln1b,
    uint16_t* __restrict__ WqT, uint16_t* __restrict__ WkT,
    uint16_t* __restrict__ WvT, uint16_t* __restrict__ WoT,
    uint16_t* __restrict__ Wff, uint16_t* __restrict__ WwgT,
    float* __restrict__ bcat, float* __restrict__ bcatFF,
    uint16_t* __restrict__ xs)
{
  __shared__ float tile[32][33];
  __shared__ float red[8];
  const int id = blockIdx.x;
  const int tid = threadIdx.x;

  if (id < 13312){
    if (id < 4096){
      int w = id >> 10, r = id & 1023;
      const float* in = (w==0)?Wq:(w==1)?Wk:(w==2)?Wv:Wo;
      uint16_t* outp  = (w==0)?WqT:(w==1)?WkT:(w==2)?WvT:WoT;
      int c0 = (r & 31)*32, r0 = (r >> 5)*32;
      int tx = tid & 31, ty = tid >> 5;
      #pragma unroll
      for (int i=0;i<4;i++) tile[ty+i*8][tx] = in[(size_t)(r0+ty+i*8)*1024 + c0+tx];
      __syncthreads();
      #pragma unroll
      for (int i=0;i<4;i++) outp[(size_t)(c0+ty+i*8)*1024 + r0+tx] = f2bf(tile[tx][ty+i*8]);
    } else if (id < 10240){
      int r = id - 4096; int s = r / 3072; r -= s*3072;
      const float* in = s ? Wvg : Wkg;
      int c0 = (r % 96)*32, r0 = (r / 96)*32;
      int tx = tid & 31, ty = tid >> 5;
      #pragma unroll
      for (int i=0;i<4;i++) tile[ty+i*8][tx] = in[(size_t)(r0+ty+i*8)*3072 + c0+tx];
      __syncthreads();
      #pragma unroll
      for (int i=0;i<4;i++){
        int j = c0+ty+i*8;                       // ffn col 0..3071
        int row = ((j>>4)<<5) + (s<<4) + (j&15); // interleaved 16-wide groups
        Wff[(size_t)row*1024 + r0+tx] = f2bf(tile[tx][ty+i*8]);
      }
    } else {
      int r = id - 10240;
      int c0 = (r & 31)*32, r0 = (r >> 5)*32;
      int tx = tid & 31, ty = tid >> 5;
      #pragma unroll
      for (int i=0;i<4;i++) tile[ty+i*8][tx] = Wwg[(size_t)(r0+ty+i*8)*1024 + c0+tx];
      __syncthreads();
      #pragma unroll
      for (int i=0;i<4;i++) WwgT[(size_t)(c0+ty+i*8)*3072 + r0+tx] = f2bf(tile[tx][ty+i*8]);
    }
    return;
  }
  if (id < 13324){
    int i = (id - 13312)*256 + tid;   // 3072
    float v;
    if      (i < 1024) v = bq[i];
    else if (i < 2048) v = bk[i-1024];
    else               v = bv[i-2048];
    bcat[i] = v;
    return;
  }
  if (id < 13348){
    int i = (id - 13324)*256 + tid;   // 6144 interleaved
    int s = (i >> 4) & 1;
    int j = ((i >> 5) << 4) | (i & 15);
    bcatFF[i] = s ? bvg[j] : bkg[j];
    return;
  }
  // ---- LN1 + shift ----
  {
    int row = id - 13348;               // b*T + t
    int t = row & (T_-1);
    const float* xr = x + (size_t)row*C_;
    float4 v = reinterpret_cast<const float4*>(xr)[tid];
    float s  = v.x+v.y+v.z+v.w;
    float s2 = v.x*v.x+v.y*v.y+v.z*v.z+v.w*v.w;
    #pragma unroll
    for (int o=1;o<64;o<<=1){ s += __shfl_xor(s,o); s2 += __shfl_xor(s2,o); }
    int lane = tid & 63, wv = tid >> 6;
    if (lane == 0){ red[wv] = s; red[4+wv] = s2; }
    __syncthreads();
    s  = red[0]+red[1]+red[2]+red[3];
    s2 = red[4]+red[5]+red[6]+red[7];
    float mean = s * (1.f/1024.f);
    float var  = s2 * (1.f/1024.f) - mean*mean;
    float rs   = rsqrtf(var + 1e-5f);
    float vals[4] = {v.x, v.y, v.z, v.w};
    #pragma unroll
    for (int j=0;j<4;j++){
      int cc = tid*4 + j;
      float o_ = (vals[j]-mean)*rs*ln1w[cc] + ln1b[cc];
      uint16_t ob = f2bf(o_);
      if (cc < 512){
        if (t < T_-1) xs[(size_t)(row+1)*C_ + cc] = ob;
        if (t == 0)   xs[(size_t)row*C_ + cc] = 0;
      } else {
        xs[(size_t)row*C_ + cc] = ob;
      }
    }
  }
}

// ---------------- LayerNorm (plain) ----------------
__global__ __launch_bounds__(256) void k_ln(const float* __restrict__ in,
                                            const float* __restrict__ w,
                                            const float* __restrict__ bia,
                                            uint16_t* __restrict__ out){
  int row = blockIdx.x;
  const float* xr = in + (size_t)row*C_;
  float4 v = reinterpret_cast<const float4*>(xr)[threadIdx.x];
  float s  = v.x+v.y+v.z+v.w;
  float s2 = v.x*v.x+v.y*v.y+v.z*v.z+v.w*v.w;
  #pragma unroll
  for (int o=1;o<64;o<<=1){ s += __shfl_xor(s,o); s2 += __shfl_xor(s2,o); }
  __shared__ float red[8];
  int lane = threadIdx.x & 63, wid = threadIdx.x >> 6;
  if (lane == 0){ red[wid] = s; red[4+wid] = s2; }
  __syncthreads();
  s  = red[0]+red[1]+red[2]+red[3];
  s2 = red[4]+red[5]+red[6]+red[7];
  float mean = s * (1.f/1024.f);
  float var  = s2 * (1.f/1024.f) - mean*mean;
  float rs   = rsqrtf(var + 1e-5f);
  float vals[4] = {v.x, v.y, v.z, v.w};
  #pragma unroll
  for (int j=0;j<4;j++){
    int cc = threadIdx.x*4 + j;
    out[(size_t)row*C_ + cc] = f2bf((vals[j]-mean)*rs*w[cc] + bia[cc]);
  }
}

// ---------------- MFMA GEMM v4: BK=64, XOR-swizzled LDS (src-swizzle + read-swizzle) ----------------
// tile 128 x BN, 4 waves (2x2). Chunk (row, j) of the 8x16B row holds global
// col-chunk (j ^ (row&7)); readers XOR with sw = l16&7 -> uniform bank groups.
enum { EPI_QKV=0, EPI_WO=2, EPI_GEGLU=3, EPI_FFN2=4 };

template<int EPI, int BN>
__global__ __launch_bounds__(256) void k_gemm2(
    const uint16_t* __restrict__ A, const uint16_t* __restrict__ Bt,
    const float* __restrict__ bias, void* __restrict__ outp,
    int M, int N, int K,
    const float* __restrict__ aux0, const float* __restrict__ aux1)
{
  __shared__ uint16_t As[128*64];     // 16 KB
  __shared__ uint16_t Bs[BN*64];      // 8/16 KB
  const int m0 = blockIdx.y*128, n0 = blockIdx.x*BN;
  const int tid = threadIdx.x;
  const int lane = tid & 63, wid = tid >> 6;
  const int wy = wid >> 1, wx = wid & 1;
  const int l16 = lane & 15, lr = lane >> 4;
  const int sw = l16 & 7;
  const int WN = BN/2;            // wave cols
  const int NW = BN/32;           // b-frags per wave
  const f32x4 z = {0.f,0.f,0.f,0.f};
  f32x4 acc[4][NW];
  #pragma unroll
  for (int m=0;m<4;m++)
    #pragma unroll
    for (int n=0;n<NW;n++) acc[m][n] = z;

  for (int k0 = 0; k0 < K; k0 += 64){
    #pragma unroll
    for (int r4=0;r4<4;r4++){
      int c = tid + r4*256;           // 1024 A-chunks
      int row = c >> 3, jp = c & 7;
      int col = ((jp ^ (row & 7)) << 3);
      gl_lds16(A + (size_t)(m0+row)*K + k0 + col, As + c*8);
    }
    #pragma unroll
    for (int r4=0;r4<BN/32;r4++){
      int c = tid + r4*256;           // BN*8 B-chunks
      int row = c >> 3, jp = c & 7;
      int col = ((jp ^ (row & 7)) << 3);
      gl_lds16(Bt + (size_t)(n0+row)*K + k0 + col, Bs + c*8);
    }
    __syncthreads();
    #pragma unroll
    for (int kk=0;kk<2;kk++){
      bf16x8 af[4], bfr[NW];
      #pragma unroll
      for (int m=0;m<4;m++)
        af[m] = ldb8(As + (wy*64 + m*16 + l16)*64 + (((lr + 4*kk) ^ sw) << 3));
      #pragma unroll
      for (int n=0;n<NW;n++)
        bfr[n] = ldb8(Bs + (wx*WN + n*16 + l16)*64 + (((lr + 4*kk) ^ sw) << 3));
      #pragma unroll
      for (int m=0;m<4;m++)
        #pragma unroll
        for (int n=0;n<NW;n++) acc[m][n] = mfma16(af[m], bfr[n], acc[m][n]);
    }
    __syncthreads();
  }
  if constexpr (EPI == EPI_QKV){
    // BN=64: one (kind,head) per block; wx==0 holds rotary pairs (d,d+16) as (n=0,n=1)
    const float linvf = exp2f(-(float)l16 * 0.83048202f);  // 10000^(-l16/16)
    #pragma unroll
    for (int m=0;m<4;m++){
      #pragma unroll
      for (int r=0;r<4;r++){
        int row = m0 + wy*64 + m*16 + lr*4 + r;
        int bb = row >> 10, t = row & 1023;
        int col0 = n0 + wx*32 + l16;
        float v0 = acc[m][0][r] + bias[col0];
        float v1 = acc[m][1][r] + bias[col0+16];
        int kind = col0 >> 10, hcol = col0 & 1023;
        int h = hcol >> 6, d0 = hcol & 63;
        if (kind < 2 && wx == 0){
          float sn, cs;
          __sincosf((float)t * linvf, &sn, &cs);
          float r0 = v0*cs - v1*sn;
          float r1 = v1*cs + v0*sn;
          v0 = r0; v1 = r1;
        }
        uint16_t* dst = (uint16_t*)outp + (size_t)kind*2097152;
        if (kind < 2){
          size_t basei = (((size_t)bb*16 + h)*1024 + t)*64;
          dst[basei + d0]      = f2bf(v0);
          dst[basei + d0 + 16] = f2bf(v1);
        } else {  // V transposed [b,h,d,t]
          size_t basei = ((size_t)bb*16 + h)*65536;
          dst[basei + (size_t)d0*1024 + t]      = f2bf(v0);
          dst[basei + (size_t)(d0+16)*1024 + t] = f2bf(v1);
        }
      }
    }
  } else if constexpr (EPI == EPI_GEGLU){
    // BN=128, interleaved Wff: frag n even = kg, n odd = vg (same thread pair)
    const int colb = n0 + wx*WN;
    #pragma unroll
    for (int m=0;m<4;m++){
      #pragma unroll
      for (int r=0;r<4;r++){
        int row = m0 + wy*64 + m*16 + lr*4 + r;
        #pragma unroll
        for (int np=0;np<NW;np+=2){
          float kk = acc[m][np][r]   + bias[colb + np*16 + l16];
          float vv = acc[m][np+1][r] + bias[colb + (np+1)*16 + l16];
          float gl = 0.5f*kk*(1.f + erff(kk*0.70710678118f));
          int j = ((colb>>5) + (np>>1))*16 + l16;      // original ffn col
          ((uint16_t*)outp)[(size_t)row*3072 + j] = f2bf(gl*vv);
        }
      }
    }
  } else {
    #pragma unroll
    for (int m=0;m<4;m++){
      #pragma unroll
      for (int n=0;n<NW;n++){
        int col = n0 + wx*WN + n*16 + l16;
        float bc_ = bias ? bias[col] : 0.f;
        #pragma unroll
        for (int r=0;r<4;r++){
          int row = m0 + wy*64 + m*16 + lr*4 + r;
          float v = acc[m][n][r] + bc_;
          if constexpr (EPI == EPI_WO){
            int t = row & (T_-1);
            ((float*)outp)[(size_t)row*N + col] = aux1[(size_t)row*N + col] + v*aux0[t];
          } else { // EPI_FFN2
            ((float*)outp)[(size_t)row*N + col] = aux0[(size_t)row*N + col] + v;
          }
        }
      }
    }
  }
}

// ---------------- pass A: softmax stats via per-lane ONLINE accumulation ----------------
__global__ __launch_bounds__(256) void k_stats(const uint16_t* __restrict__ q,
                                               const uint16_t* __restrict__ kmat,
                                               float* __restrict__ sm, float* __restrict__ sl){
  int bh = blockIdx.x, qb = blockIdx.y;
  int lane = threadIdx.x & 63, wid = threadIdx.x >> 6;
  int l16 = lane & 15, lr = lane >> 4;
  int r0 = qb*64 + wid*16;
  const uint16_t* qh = q    + (size_t)bh*T_*HS_;
  const uint16_t* kh = kmat + (size_t)bh*T_*HS_;
  int kq = lr*8;
  bf16x8 a0 = ldb8(qh + (size_t)(r0 + l16)*HS_ + kq);
  bf16x8 a1 = ldb8(qh + (size_t)(r0 + l16)*HS_ + kq + 32);
  float m_[4], l_[4]; int rows[4];
  #pragma unroll
  for (int r=0;r<4;r++){ m_[r] = -1e30f; l_[r] = 0.f; rows[r] = r0 + lr*4 + r; }
  int ktmax = (r0 + 15) >> 4;
  for (int kt = 0; kt <= ktmax; kt++){
    bf16x8 b0 = ldb8(kh + (size_t)(kt*16 + l16)*HS_ + kq);
    bf16x8 b1 = ldb8(kh + (size_t)(kt*16 + l16)*HS_ + kq + 32);
    f32x4 s = {0.f,0.f,0.f,0.f};
    s = mfma16(a0, b0, s);
    s = mfma16(a1, b1, s);
    int kcol = kt*16 + l16;
    #pragma unroll
    for (int r=0;r<4;r++){
      float sv = (kcol <= rows[r]) ? s[r]*0.125f : -3.0e38f;
      float mn = fmaxf(m_[r], sv);
      l_[r] = l_[r]*__expf(m_[r] - mn) + __expf(sv - mn);
      m_[r] = mn;
    }
  }
  #pragma unroll
  for (int o=1;o<16;o<<=1){
    #pragma unroll
    for (int r=0;r<4;r++){
      float mo = __shfl_xor(m_[r], o);
      float lo = __shfl_xor(l_[r], o);
      float mn = fmaxf(m_[r], mo);
      l_[r] = l_[r]*__expf(m_[r] - mn) + lo*__expf(mo - mn);
      m_[r] = mn;
    }
  }
  if (l16 == 0){
    #pragma unroll
    for (int r=0;r<4;r++){
      sm[(size_t)bh*T_ + rows[r]] = m_[r];
      sl[(size_t)bh*T_ + rows[r]] = l_[r];
    }
  }
}

// ---------------- fused attention v9: persistent queue + V-prefetch (VGPR-safe, 120 regs) ----------------
// NOTE: 512-thr blocks at 2 blocks/CU => per-wave VGPR ceiling is 128. v9 fits (120).
// Register K-prefetch (v10) exceeded it and spilled — do not re-add.
__global__ __launch_bounds__(512, 2) void k_attn(
    const uint16_t* __restrict__ q, const uint16_t* __restrict__ kmat,
    const uint16_t* __restrict__ vT,
    const float* __restrict__ sm, const float* __restrict__ sl,
    const float* __restrict__ tw, const float* __restrict__ alpha,
    const float* __restrict__ beta, const float* __restrict__ mixw,
    uint16_t* __restrict__ py, int* __restrict__ counter)
{
  __shared__ uint32_t U32[2*4096];     // 32 KB: two tile buffers
  __shared__ uint16_t Cm[2*8320];      // 33.3 KB
  __shared__ uint16_t TWL[16*160];     // 5 KB (bf16)
  __shared__ int s_item;

  const int tid = threadIdx.x;
  const int lane = tid & 63;
  const int wid = __builtin_amdgcn_readfirstlane(tid >> 6);
  const int l16 = lane & 15, lr = lane >> 4;
  const int l32 = lane & 31, g32 = lane >> 5;

  // mix-weight B-fragment (item-independent)
  bf16x8 mwf;
  {
    u16x8 t8;
    #pragma unroll
    for (int j=0;j<8;j++){
      float v = (l32 < 16) ? mixw[l32*16 + g32*8 + j] : 0.f;
      t8[j] = f2bf(v);
    }
    mwf = __builtin_bit_cast(bf16x8, t8);
  }
  const f32x4 z = {0.f,0.f,0.f,0.f};

  for (;;){
    if (tid == 0) s_item = atomicAdd(counter, 1);
    __syncthreads();
    const int item = s_item;
    if (item >= 576) break;

    // decode item -> (b, qt, kc)
    const int b = (item >= 288) ? 1 : 0;
    int j = item - b*288;
    int g = 0;
    while (4*(g+1)*(g+2) <= j) g++;
    int jj = j - 4*g*(g+1);
    const int qt = 8*g + jj/(g+1);
    const int kc = jj % (g+1);

    const int q0 = qt*16, ck0 = kc*128;
    const int lc = min(127, q0 + 15 - ck0);
    const int nt = (lc >> 5) + 1;

    // per-item staging
    const int base = 1008 - q0 + ck0;
    for (int i = tid; i < 16*144; i += 512){
      int h = i / 144, t = i - h*144;
      int gi = base + t;
      TWL[h*160 + t] = (gi <= 1023) ? f2bf(tw[h*1024 + gi]) : (uint16_t)0;
    }
    float SM[2][4], BSL[2][4];
    bf16x8 qa[2][2];
    #pragma unroll
    for (int h2=0; h2<2; ++h2){
      int h = 2*wid + h2, bh = b*16 + h;
      float4 s4 = *reinterpret_cast<const float4*>(sm   + (size_t)bh*1024 + q0 + lr*4);
      float4 l4 = *reinterpret_cast<const float4*>(sl   + (size_t)bh*1024 + q0 + lr*4);
      float4 b4 = *reinterpret_cast<const float4*>(beta + (size_t)h*1024  + q0 + lr*4);
      SM[h2][0]=s4.x; SM[h2][1]=s4.y; SM[h2][2]=s4.z; SM[h2][3]=s4.w;
      BSL[h2][0]=b4.x/l4.x; BSL[h2][1]=b4.y/l4.y; BSL[h2][2]=b4.z/l4.z; BSL[h2][3]=b4.w/l4.w;
      #pragma unroll
      for (int kk=0;kk<2;kk++)
        qa[h2][kk] = ldb8(q + ((size_t)bh*1024 + q0 + l16)*64 + kk*32 + lr*8);
    }
    f32x4 acc[2][4];
    #pragma unroll
    for (int oo=0;oo<2;oo++) for (int n=0;n<4;n++) acc[oo][n] = z;

    __syncthreads();   // TWL ready

    for (int tp = 0; tp < nt; tp += 2){
      const int ntile = (nt - tp >= 2) ? 2 : 1;
      bf16x8 vf[2][2][4];   // [half][oo][n], live across B1/B2 (fits 128-VGPR budget)
      // ---- phase 1: V prefetch + QK^T + u for each half ----
      #pragma unroll
      for (int half = 0; half < 2; ++half){
        if (half >= ntile) break;
        const int t = tp + half;
        const int k0 = ck0 + t*32;
        // V prefetch (consumed in phase 3, ~2 barriers + mix later)
        #pragma unroll
        for (int oo=0;oo<2;oo++){
          const uint16_t* vh = vT + (size_t)(b*16 + 2*wid + oo)*65536;
          #pragma unroll
          for (int n=0;n<4;n++)
            vf[half][oo][n] = ldb8(vh + (size_t)(n*16 + l16)*1024 + k0 + lr*8);
        }
        float al0[2], al1[2];
        #pragma unroll
        for (int n=0;n<2;n++){
          int kg = k0 + n*16 + l16;
          al0[n] = alpha[(2*wid+0)*1024 + kg];
          al1[n] = alpha[(2*wid+1)*1024 + kg];
        }
        f32x4 s[2][2];
        s[0][0]=z; s[0][1]=z; s[1][0]=z; s[1][1]=z;
        #pragma unroll
        for (int h2=0;h2<2;h2++){
          const uint16_t* kh = kmat + ((size_t)(b*16 + 2*wid + h2)*1024 + k0)*64;
          #pragma unroll
          for (int kk=0;kk<2;kk++){
            bf16x8 kb0 = ldb8(kh + (size_t)(l16)*64      + kk*32 + lr*8);
            bf16x8 kb1 = ldb8(kh + (size_t)(16 + l16)*64 + kk*32 + lr*8);
            s[h2][0] = mfma16(qa[h2][kk], kb0, s[h2][0]);
            s[h2][1] = mfma16(qa[h2][kk], kb1, s[h2][1]);
          }
        }
        uint32_t* Ub = U32 + half*4096;
        #pragma unroll
        for (int n=0;n<2;n++){
          int kloc = n*16 + l16;
          int kg = k0 + kloc;
          #pragma unroll
          for (int r=0;r<4;r++){
            int qloc = lr*4 + r;
            bool ok = (kg <= q0 + qloc);
            int twi = 15 - qloc + (kg - ck0);
            float u0 = 0.f, u1 = 0.f;
            if (ok){
              u0 = __expf(s[0][n][r]*0.125f - SM[0][r]) * BSL[0][r] * al0[n] * bf2f(TWL[(2*wid+0)*160 + twi]);
              u1 = __expf(s[1][n][r]*0.125f - SM[1][r]) * BSL[1][r] * al1[n] * bf2f(TWL[(2*wid+1)*160 + twi]);
            }
            uint32_t pk = (uint32_t)f2bf(u0) | ((uint32_t)f2bf(u1) << 16);
            Ub[wid*512 + qloc*32 + ((kloc + 8*(qloc>>2)) & 31)] = pk;
          }
        }
      }
      __syncthreads();   // B1: U buffers complete
      // ---- phase 2: head-mix via 32x32x16 MFMA ----
      #pragma unroll
      for (int half = 0; half < 2; ++half){
        if (half >= ntile) break;
        const uint32_t* Ub = U32 + half*4096;
        uint16_t* Cb = Cm + half*8320;
        #pragma unroll
        for (int cc=0; cc<2; ++cc){
          int qrow = wid*2 + cc;
          int pbase = qrow*32;
          int swz = (l32 + 8*(qrow>>2)) & 31;
          u16x8 a8;
          uint32_t* a32 = reinterpret_cast<uint32_t*>(&a8);
          #pragma unroll
          for (int jv=0;jv<4;jv++)
            a32[jv] = Ub[(4*g32 + jv)*512 + pbase + swz];
          bf16x8 a = __builtin_bit_cast(bf16x8, a8);
          f32x16 zz{};
          __builtin_amdgcn_s_setprio(1);
          f32x16 dd = __builtin_amdgcn_mfma_f32_32x32x16_bf16(a, mwf, zz, 0, 0, 0);
          __builtin_amdgcn_s_setprio(0);
          if (l32 < 16){
            int o = l32;
            #pragma unroll
            for (int rg=0; rg<4; ++rg){
              int p0 = pbase + rg*8 + g32*4;
              uint32_t w0 = (uint32_t)f2bf(dd[4*rg+0]) | ((uint32_t)f2bf(dd[4*rg+1]) << 16);
              uint32_t w1 = (uint32_t)f2bf(dd[4*rg+2]) | ((uint32_t)f2bf(dd[4*rg+3]) << 16);
              uint2 pk2; pk2.x = w0; pk2.y = w1;
              *reinterpret_cast<uint2*>(Cb + (size_t)o*520 + p0) = pk2;
            }
          }
        }
      }
      __syncthreads();   // B2: Cm buffers complete
      // ---- phase 3: PV both halves with prefetched V ----
      #pragma unroll
      for (int half = 0; half < 2; ++half){
        if (half >= ntile) break;
        const uint16_t* Cb = Cm + half*8320;
        #pragma unroll
        for (int oo=0;oo<2;oo++){
          int o = 2*wid + oo;
          bf16x8 cf = ldb8(Cb + (size_t)o*520 + l16*32 + lr*8);
          __builtin_amdgcn_s_setprio(1);
          #pragma unroll
          for (int n=0;n<4;n++)
            acc[oo][n] = mfma16(cf, vf[half][oo][n], acc[oo][n]);
          __builtin_amdgcn_s_setprio(0);
        }
      }
    }

    uint16_t* po = py + (((size_t)(b*64 + qt))*8 + kc)*16384;
    #pragma unroll
    for (int oo=0;oo<2;oo++){
      int o = 2*wid + oo;
      #pragma unroll
      for (int n=0;n<4;n++)
        #pragma unroll
        for (int r=0;r<4;r++){
          int qloc = lr*4 + r;
          po[o*1024 + qloc*64 + n*16 + l16] = f2bf(acc[oo][n][r]);
        }
    }
    __syncthreads();   // all phases done before next pop / LDS reuse
  }
}

// ---------------- reduce bf16 partials -> ybuf bf16 [B,T,C] ----------------
__global__ void k_yred(const uint16_t* __restrict__ py, uint16_t* __restrict__ y){
  int idx = blockIdx.x*256 + threadIdx.x;   // 262144, one bf16x8 each
  int d8 = idx & 7, qq = (idx>>3)&15, o = (idx>>7)&15, qt = (idx>>11)&63, b = idx>>17;
  int nch = (qt>>3) + 1;
  const uint16_t* p0 = py + (((size_t)(b*64+qt))*8)*16384 + o*1024 + qq*64 + d8*8;
  float s[8] = {0,0,0,0,0,0,0,0};
  for (int kc=0; kc<nch; kc++){
    u16x8 v = *reinterpret_cast<const u16x8*>(p0 + (size_t)kc*16384);
    #pragma unroll
    for (int e=0;e<8;e++) s[e] += bf2f(v[e]);
  }
  int t = qt*16 + qq;
  u16x8 w;
  #pragma unroll
  for (int e=0;e<8;e++) w[e] = f2bf(s[e]);
  *reinterpret_cast<u16x8*>(y + ((size_t)(b*1024 + t))*1024 + o*64 + d8*8) = w;
}

// ---------------- host ----------------
extern "C" void kernel_launch(void* const* d_in, const int* in_sizes, int n_in,
                              void* d_out, int out_size, void* d_ws, size_t ws_size,
                              hipStream_t stream)
{
  const float* x      = (const float*)d_in[0];
  const float* ln1w   = (const float*)d_in[1];
  const float* ln1b   = (const float*)d_in[2];
  const float* ln2w   = (const float*)d_in[3];
  const float* ln2b   = (const float*)d_in[4];
  const float* Wq     = (const float*)d_in[5];
  const float* bq     = (const float*)d_in[6];
  const float* Wk     = (const float*)d_in[7];
  const float* bk     = (const float*)d_in[8];
  const float* Wv     = (const float*)d_in[9];
  const float* bv     = (const float*)d_in[10];
  const float* Wo     = (const float*)d_in[11];
  const float* bo     = (const float*)d_in[12];
  const float* tw     = (const float*)d_in[13];
  const float* talpha = (const float*)d_in[14];
  const float* tbeta  = (const float*)d_in[15];
  const float* tgamma = (const float*)d_in[16];
  const float* mixw   = (const float*)d_in[17];
  const float* Wkg    = (const float*)d_in[18];
  const float* bkg    = (const float*)d_in[19];
  const float* Wvg    = (const float*)d_in[20];
  const float* bvg    = (const float*)d_in[21];
  const float* Wwg    = (const float*)d_in[22];
  const float* bwg    = (const float*)d_in[23];

  char* ws = (char*)d_ws;
  size_t off = 0;
  auto alloc = [&](size_t bytes)->char*{
    char* p = ws + off; off += (bytes + 255) & ~(size_t)255; return p;
  };
  int*      counter = (int*)alloc(256);
  uint16_t* WqT  = (uint16_t*)alloc((size_t)C_*C_*2);     // contiguous q|k|v
  uint16_t* WkT  = (uint16_t*)alloc((size_t)C_*C_*2);
  uint16_t* WvT  = (uint16_t*)alloc((size_t)C_*C_*2);
  uint16_t* WoT  = (uint16_t*)alloc((size_t)C_*C_*2);
  uint16_t* Wff  = (uint16_t*)alloc((size_t)2*FFN_*C_*2); // interleaved kg|vg
  uint16_t* WwgT = (uint16_t*)alloc((size_t)C_*FFN_*2);
  uint16_t* xs   = (uint16_t*)alloc((size_t)B_*T_*C_*2);
  uint16_t* qbuf = (uint16_t*)alloc((size_t)B_*T_*C_*2);  // contiguous q|k|vT
  uint16_t* kbuf = (uint16_t*)alloc((size_t)B_*T_*C_*2);
  uint16_t* vT   = (uint16_t*)alloc((size_t)B_*T_*C_*2);
  float*    sm   = (float*)alloc((size_t)B_*H_*T_*4);
  float*    sl   = (float*)alloc((size_t)B_*H_*T_*4);
  uint16_t* ybuf = (uint16_t*)alloc((size_t)B_*T_*C_*2);
  float*    x1   = (float*)alloc((size_t)B_*T_*C_*4);
  float*    bcat   = (float*)alloc((size_t)3072*4);
  float*    bcatFF = (float*)alloc((size_t)6144*4);
  char*     region = alloc((size_t)33*1024*1024);
  uint16_t* py  = (uint16_t*)region;                       // 32 MB bf16 partials
  uint16_t* gb  = (uint16_t*)region;                       // 12.6 MB (after attn done)

  if (off > ws_size){
    fprintf(stderr, "kernel_launch: ws too small (%zu needed, %zu given)\n", off, ws_size);
    return;
  }

  hipMemsetAsync(counter, 0, 4, stream);

  dim3 blk(256);
  // fused prologue: 7 transposes + biases + LN1/shift
  k_prep<<<15396, blk, 0, stream>>>(Wq, Wk, Wv, Wo, Wkg, Wvg, Wwg,
                                    bq, bk, bv, bkg, bvg,
                                    x, ln1w, ln1b,
                                    WqT, WkT, WvT, WoT, Wff, WwgT,
                                    bcat, bcatFF, xs);

  // fused QKV (N=3072) with RoPE + scatter epilogue, BN=64
  k_gemm2<EPI_QKV,64><<<dim3(48,16), blk, 0, stream>>>(xs, WqT, bcat, qbuf, 2048, 3072, 1024, nullptr, nullptr);

  k_stats<<<dim3(B_*H_, T_/64), blk, 0, stream>>>(qbuf, kbuf, sm, sl);
  k_attn<<<dim3(512), dim3(512), 0, stream>>>(qbuf, kbuf, vT, sm, sl,
                                              tw, talpha, tbeta, mixw, py, counter);
  k_yred<<<1024, blk, 0, stream>>>(py, ybuf);

  k_gemm2<EPI_WO,64><<<dim3(16,16), blk, 0, stream>>>(ybuf, WoT, bo, x1, 2048, 1024, 1024, tgamma, x);

  k_ln<<<B_*T_, blk, 0, stream>>>(x1, ln2w, ln2b, xs);

  // fused FFN-up + GEGLU (N=6144 interleaved -> gb 3072)
  k_gemm2<EPI_GEGLU,128><<<dim3(48,16), blk, 0, stream>>>(xs, Wff, bcatFF, gb, 2048, 6144, 1024, nullptr, nullptr);
  k_gemm2<EPI_FFN2,64><<<dim3(16,16), blk, 0, stream>>>(gb, WwgT, bwg, d_out, 2048, 1024, 3072, x1, nullptr);
}